// Round 10
// baseline (477.326 us; speedup 1.0000x reference)
//
#include <hip/hip_runtime.h>
#include <hip/hip_bf16.h>

// x:[1024,3,32,32] -> conv1(3->64)+relu -> conv2(64->128)+relu -> meanpool
// -> fc(128->256)+b -> *mask -> sage1(256->256)+relu -> sage2(256->128)
// Output [32,32,128] fp32.
//
// Workspace layout:
//  [0,4M)          pooled8 [1024][8][128] f32 (band partials, pre-divide)
//  [4096K,+256K)   l1T  [256][256] = s1lw^T
//  [4352K,+256K)   w1pT [256][256] = (s1rw - s1lw/31)^T
//  [4608K,+128K)   l2T  [256][128] = s2lw^T
//  [4736K,+128K)   w2pT [256][128] = (s2rw - s2lw/31)^T
//  [4864K,+128K)   fwT  [128][256] = fc_w^T
//  [4992K,+144K)   w2b  [9][128][64] bf16 conv2 w, tap-major
//  [5136K,+4K)     w1b  [64][32] bf16 conv1 w+bias (k=27 slot = bias)
//  [6M, ...)       c1full chunk: imgs_per_pass x [32][32][64] bf16 (128KB/img)

typedef __attribute__((ext_vector_type(8))) short bfrag;
typedef __attribute__((ext_vector_type(4))) float f32x4;

static __device__ __forceinline__ unsigned short f2bf(float f) {
    union { float f; unsigned u; } v; v.f = f;
    unsigned r = v.u + 0x7fff + ((v.u >> 16) & 1);   // RNE (finite)
    return (unsigned short)(r >> 16);
}

__global__ __launch_bounds__(256) void prep_kernel(
    const float* __restrict__ s1lw, const float* __restrict__ s1rw,
    const float* __restrict__ s2lw, const float* __restrict__ s2rw,
    const float* __restrict__ c2w, const float* __restrict__ c1w,
    const float* __restrict__ c1b, const float* __restrict__ fcw,
    float* __restrict__ l1T, float* __restrict__ w1pT,
    float* __restrict__ l2T, float* __restrict__ w2pT,
    float* __restrict__ fwT,
    short* __restrict__ w2b, short* __restrict__ w1b) {
    int i = blockIdx.x * 256 + threadIdx.x;     // grid 288 -> [0, 73728)
    const float inv31 = 1.f / 31.f;
    if (i < 65536) {
        int d = i >> 8, o = i & 255;
        float lw = s1lw[o * 256 + d];
        l1T[i]  = lw;
        w1pT[i] = s1rw[o * 256 + d] - lw * inv31;
    }
    if (i < 32768) {
        int d = i >> 7, o = i & 127;
        float lw = s2lw[o * 256 + d];
        l2T[i]  = lw;
        w2pT[i] = s2rw[o * 256 + d] - lw * inv31;
        int c = i >> 8, o2 = i & 255;
        fwT[i] = fcw[o2 * 128 + c];
    }
    if (i < 73728) {                            // w2b[k][oc][ic] = c2w[oc][ic][k]
        int k = i >> 13, rem = i & 8191, oc = rem >> 6, ic = rem & 63;
        w2b[i] = (short)f2bf(c2w[(oc * 64 + ic) * 9 + k]);
    }
    if (i < 2048) {                             // w1b[oc][k], k=27 -> bias
        int oc = i >> 5, k = i & 31;
        float v = (k < 27) ? c1w[oc * 27 + k] : (k == 27 ? c1b[oc] : 0.f);
        w1b[i] = (short)f2bf(v);
    }
}

// conv1: grid (8 bands, imgs). One 4-row band per block; stage only 6 input rows.
__global__ __launch_bounds__(256, 4) void conv1_kernel(
    const float* __restrict__ x, const short* __restrict__ w1b,
    short* __restrict__ c1full, int img0) {
    const int band = blockIdx.x, limg = blockIdx.y, img = img0 + limg;
    __shared__ short xt[3 * 6 * 34];      // 1224 B: rows y0-1..y0+4, cols padded
    __shared__ short a1t[128 * 36];       // 9216 B im2col (K pad 36)
    __shared__ short c1band[4 * 32 * 64]; // 16384 B band output
    const int t = threadIdx.x;
    const int w = t >> 6, lane = t & 63;
    const int ln15 = lane & 15, q8 = (lane >> 4) * 8;
    const int y0 = band * 4;

    const float* xi = x + img * 3072;
    for (int idx = t; idx < 612; idx += 256) {
        int c = idx / 204, rem = idx % 204, r = rem / 34, col = rem % 34;
        int y = y0 + r - 1, xx = col - 1;
        float v = 0.f;
        if ((unsigned)y < 32u && (unsigned)xx < 32u) v = xi[c * 1024 + y * 32 + xx];
        xt[idx] = (short)f2bf(v);
    }
    bfrag b1f[4];
#pragma unroll
    for (int ot = 0; ot < 4; ++ot)
        b1f[ot] = *(const bfrag*)(w1b + (ot * 16 + ln15) * 32 + q8);
    __syncthreads();

    // im2col: 128 pos x 32 k; 2 threads per pos (k halves)
    {
        int p = t >> 1, r = p >> 5, xc = p & 31;
        short* ap = &a1t[p * 36];
        if ((t & 1) == 0) {
#pragma unroll
            for (int k = 0; k < 16; ++k) {
                int c = k / 9, rem = k - c * 9, dy = rem / 3, dx = rem - dy * 3;
                ap[k] = xt[c * 204 + (r + dy) * 34 + xc + dx];
            }
        } else {
#pragma unroll
            for (int k = 16; k < 27; ++k) {
                int c = k / 9, rem = k - c * 9, dy = rem / 3, dx = rem - dy * 3;
                ap[k] = xt[c * 204 + (r + dy) * 34 + xc + dx];
            }
            ap[27] = (short)0x3F80;              // 1.0 bias slot
            ap[28] = 0; ap[29] = 0; ap[30] = 0; ap[31] = 0;
        }
    }
    __syncthreads();
    // mfma: 8 pos-tiles of 16; wave w -> tiles 2w, 2w+1
#pragma unroll
    for (int pt = 0; pt < 2; ++pt) {
        const int tile = w * 2 + pt;
        bfrag a1f = *(const bfrag*)(&a1t[(tile * 16 + ln15) * 36 + q8]);
        f32x4 acc1[4];
#pragma unroll
        for (int ot = 0; ot < 4; ++ot) {
#pragma unroll
            for (int rg = 0; rg < 4; ++rg) acc1[ot][rg] = 0.f;
            acc1[ot] = __builtin_amdgcn_mfma_f32_16x16x32_bf16(
                a1f, b1f[ot], acc1[ot], 0, 0, 0);
        }
#pragma unroll
        for (int rg = 0; rg < 4; ++rg) {
            int pos = tile * 16 + (lane >> 4) * 4 + rg;   // 0..127
            int r = pos >> 5, xc = pos & 31;
#pragma unroll
            for (int ot = 0; ot < 4; ++ot)
                c1band[(r * 32 + xc) * 64 + ot * 16 + ln15] =
                    (short)f2bf(fmaxf(acc1[ot][rg], 0.f));
        }
    }
    __syncthreads();
    // copy band -> global (16384 B contiguous)
    {
        const f32x4* src = (const f32x4*)c1band;
        f32x4* dst = (f32x4*)(c1full + (size_t)limg * 65536 + band * 8192);
        for (int idx = t; idx < 1024; idx += 256) dst[idx] = src[idx];
    }
}

// conv2+pool: grid (8 bands of 4 rows, imgs). Wave = 64 pos x 64 oc, acc=64 regs.
// Single-buffered B; occupancy (not ILP) hides latency: LDS 29.4KB -> 5 blocks/CU
// by LDS, (256,3) caps regs at ~170 (live ~150: 64 acc + 32 B + addressing).
// r8 lesson: never cap below the live set (acc spills = 6x).
__global__ __launch_bounds__(256, 3) void conv2_kernel(
    const short* __restrict__ c1full, const short* __restrict__ w2b,
    const float* __restrict__ b2, float* __restrict__ pooled8, int img0) {
    const int band = blockIdx.x, limg = blockIdx.y, img = img0 + limg;
    __shared__ short c1t[6 * 34 * 72];    // 29376 B [row 0..5][col pad34][ic pad72]
    __shared__ float wsum[4][64];
    const int t = threadIdx.x;
    const int w = t >> 6, lane = t & 63;
    const int ln15 = lane & 15, q8 = (lane >> 4) * 8;
    const int rw = w & 1, og = w >> 1;    // row-pair (2 rows), oc-group (64 oc)

    {   // targeted zeroing: pad cols 0/33 (6 rows) + OOB halo rows
        f32x4 z = {0.f, 0.f, 0.f, 0.f};
        for (int i = t; i < 96; i += 256) {           // 6r x 2c x 8 chunks
            int r = i >> 4, rem = i & 15, side = rem >> 3, q = rem & 7;
            *(f32x4*)(c1t + (r * 34 + side * 33) * 72 + q * 8) = z;
        }
        if (band == 0)
            for (int i = t; i < 272; i += 256)        // row 0 OOB: 34 cols x 8
                *(f32x4*)(c1t + (i >> 3) * 72 + (i & 7) * 8) = z;
        if (band == 7)
            for (int i = t; i < 272; i += 256)        // row 5 OOB
                *(f32x4*)(c1t + (5 * 34 + (i >> 3)) * 72 + (i & 7) * 8) = z;
    }
    {   // stage 6 rows (band*4-1 .. band*4+4), disjoint from zeroed region
        const short* src = c1full + (size_t)limg * 65536;
        for (int idx = t; idx < 1536; idx += 256) {
            int row = idx >> 8, grow = band * 4 + row - 1;
            if ((unsigned)grow < 32u) {
                int c8 = idx & 255, col = c8 >> 3, q = c8 & 7;
                *(f32x4*)(c1t + (row * 34 + col + 1) * 72 + q * 8) =
                    *(const f32x4*)(src + (grow * 32 + col) * 64 + q * 8);
            }
        }
    }
    __syncthreads();

    float b2v[4];
#pragma unroll
    for (int ot = 0; ot < 4; ++ot) b2v[ot] = b2[og * 64 + ot * 16 + ln15];

    f32x4 acc[4][4];
#pragma unroll
    for (int pt = 0; pt < 4; ++pt)
#pragma unroll
        for (int ot = 0; ot < 4; ++ot)
#pragma unroll
            for (int rg = 0; rg < 4; ++rg) acc[pt][ot][rg] = 0.f;

    const short* wb0 = w2b + (og * 64 + ln15) * 64 + q8;
#pragma unroll 1
    for (int tap = 0; tap < 9; ++tap) {
        const int dy = tap / 3, dx = tap - dy * 3;
        bfrag bf[8];
        const short* p = wb0 + tap * 8192;
#pragma unroll
        for (int kc = 0; kc < 2; ++kc)
#pragma unroll
            for (int ot = 0; ot < 4; ++ot)
                bf[kc * 4 + ot] = *(const bfrag*)(p + ot * 1024 + kc * 32);
#pragma unroll
        for (int kc = 0; kc < 2; ++kc)
#pragma unroll
            for (int pt = 0; pt < 4; ++pt) {
                int r = rw * 2 + (pt >> 1);            // out row 0..3 in band
                int xc = ((pt & 1) << 4) + ln15;
                bfrag a2f = *(const bfrag*)(
                    &c1t[((r + dy) * 34 + xc + dx) * 72 + kc * 32 + q8]);
#pragma unroll
                for (int ot = 0; ot < 4; ++ot)
                    acc[pt][ot] = __builtin_amdgcn_mfma_f32_16x16x32_bf16(
                        a2f, bf[kc * 4 + ot], acc[pt][ot], 0, 0, 0);
            }
    }

    // bias + relu + pool (wave covers 64 pos x 64 oc)
#pragma unroll
    for (int ot = 0; ot < 4; ++ot) {
        float s = 0.f;
#pragma unroll
        for (int pt = 0; pt < 4; ++pt)
#pragma unroll
            for (int rg = 0; rg < 4; ++rg)
                s += fmaxf(acc[pt][ot][rg] + b2v[ot], 0.f);
        s += __shfl_xor(s, 16, 64);
        s += __shfl_xor(s, 32, 64);
        if (lane < 16) wsum[w][ot * 16 + ln15] = s;
    }
    __syncthreads();
    if (t < 128) {
        int og2 = t >> 6, oo = t & 63;
        pooled8[((size_t)img * 8 + band) * 128 + t] =
            wsum[og2 * 2][oo] + wsum[og2 * 2 + 1][oo];
    }
}

// tail: fc + mask + sage1 + relu + sage2, one block per batch element.
__global__ __launch_bounds__(256) void tail_kernel(
    const float* __restrict__ pooled8, const float* __restrict__ fwT,
    const float* __restrict__ fb, const float* __restrict__ mask,
    const float* __restrict__ l1T, const float* __restrict__ lb1,
    const float* __restrict__ w1pT, const float* __restrict__ l2T,
    const float* __restrict__ lb2, const float* __restrict__ w2pT,
    float* __restrict__ out) {
    const int bb = blockIdx.x;
    __shared__ float m[32 * 128];
    __shared__ float hA[32 * 256];
    __shared__ float hB[32 * 256];
    __shared__ float sl[256];
    __shared__ float mk[32];
    const int t = threadIdx.x;
    if (t < 32) mk[t] = mask[bb * 32 + t];
    for (int idx = t; idx < 4096; idx += 256) {
        int n = idx >> 7, c = idx & 127;
        const float* p = pooled8 + ((size_t)(bb * 32 + n) * 8) * 128 + c;
        float s = p[0] + p[128] + p[256] + p[384]
                + p[512] + p[640] + p[768] + p[896];
        m[idx] = s * (1.f / 1024.f);
    }
    __syncthreads();
    float acc[32];
#pragma unroll
    for (int n = 0; n < 32; ++n) acc[n] = 0.f;
    for (int c0 = 0; c0 < 128; c0 += 4) {
        float wv0 = fwT[(c0 + 0) * 256 + t];
        float wv1 = fwT[(c0 + 1) * 256 + t];
        float wv2 = fwT[(c0 + 2) * 256 + t];
        float wv3 = fwT[(c0 + 3) * 256 + t];
#pragma unroll
        for (int n = 0; n < 32; ++n) {
            f32x4 hv = *(const f32x4*)&m[n * 128 + c0];
            acc[n] = fmaf(hv[0], wv0, acc[n]);
            acc[n] = fmaf(hv[1], wv1, acc[n]);
            acc[n] = fmaf(hv[2], wv2, acc[n]);
            acc[n] = fmaf(hv[3], wv3, acc[n]);
        }
    }
    {
        float fbv = fb[t];
        for (int n = 0; n < 32; ++n) hA[n * 256 + t] = (acc[n] + fbv) * mk[n];
    }
    __syncthreads();
    {
        float s = 0.f;
#pragma unroll
        for (int n = 0; n < 32; ++n) s += hA[n * 256 + t];
        sl[t] = s * (1.f / 31.f);
    }
    __syncthreads();
    {
        float c1v = lb1[t];
#pragma unroll 4
        for (int d = 0; d < 256; ++d) c1v = fmaf(sl[d], l1T[d * 256 + t], c1v);
#pragma unroll
        for (int n = 0; n < 32; ++n) acc[n] = c1v;
        for (int d0 = 0; d0 < 256; d0 += 4) {
            float wv0 = w1pT[(d0 + 0) * 256 + t];
            float wv1 = w1pT[(d0 + 1) * 256 + t];
            float wv2 = w1pT[(d0 + 2) * 256 + t];
            float wv3 = w1pT[(d0 + 3) * 256 + t];
#pragma unroll
            for (int n = 0; n < 32; ++n) {
                f32x4 hv = *(const f32x4*)&hA[n * 256 + d0];
                acc[n] = fmaf(hv[0], wv0, acc[n]);
                acc[n] = fmaf(hv[1], wv1, acc[n]);
                acc[n] = fmaf(hv[2], wv2, acc[n]);
                acc[n] = fmaf(hv[3], wv3, acc[n]);
            }
        }
        for (int n = 0; n < 32; ++n) hB[n * 256 + t] = fmaxf(acc[n], 0.f);
    }
    __syncthreads();
    {
        float s = 0.f;
#pragma unroll
        for (int n = 0; n < 32; ++n) s += hB[n * 256 + t];
        sl[t] = s * (1.f / 31.f);
    }
    __syncthreads();
    {
        const int o = t & 127, half = t >> 7;
        float c2v = lb2[o];
#pragma unroll 4
        for (int d = 0; d < 256; ++d) c2v = fmaf(sl[d], l2T[d * 128 + o], c2v);
        float a2[16];
#pragma unroll
        for (int i = 0; i < 16; ++i) a2[i] = c2v;
        for (int d0 = 0; d0 < 256; d0 += 4) {
            float wv0 = w2pT[(d0 + 0) * 128 + o];
            float wv1 = w2pT[(d0 + 1) * 128 + o];
            float wv2 = w2pT[(d0 + 2) * 128 + o];
            float wv3 = w2pT[(d0 + 3) * 128 + o];
#pragma unroll
            for (int i = 0; i < 16; ++i) {
                f32x4 hv = *(const f32x4*)&hB[(half * 16 + i) * 256 + d0];
                a2[i] = fmaf(hv[0], wv0, a2[i]);
                a2[i] = fmaf(hv[1], wv1, a2[i]);
                a2[i] = fmaf(hv[2], wv2, a2[i]);
                a2[i] = fmaf(hv[3], wv3, a2[i]);
            }
        }
        for (int i = 0; i < 16; ++i)
            out[(size_t)(bb * 32 + half * 16 + i) * 128 + o] = a2[i];
    }
}

extern "C" void kernel_launch(void* const* d_in, const int* in_sizes, int n_in,
                              void* d_out, int out_size, void* d_ws, size_t ws_size,
                              hipStream_t stream) {
    const float* x    = (const float*)d_in[0];
    const float* mask = (const float*)d_in[1];
    const float* c1w  = (const float*)d_in[2];
    const float* c1b  = (const float*)d_in[3];
    const float* c2w  = (const float*)d_in[4];
    const float* c2b  = (const float*)d_in[5];
    const float* fcw  = (const float*)d_in[6];
    const float* fcb  = (const float*)d_in[7];
    const float* s1lw = (const float*)d_in[8];
    const float* s1lb = (const float*)d_in[9];
    const float* s1rw = (const float*)d_in[10];
    const float* s2lw = (const float*)d_in[11];
    const float* s2lb = (const float*)d_in[12];
    const float* s2rw = (const float*)d_in[13];
    float* out = (float*)d_out;

    char* ws = (char*)d_ws;
    float* pooled8 = (float*)(ws);
    float* l1T     = (float*)(ws + 4096u * 1024);
    float* w1pT    = (float*)(ws + 4352u * 1024);
    float* l2T     = (float*)(ws + 4608u * 1024);
    float* w2pT    = (float*)(ws + 4736u * 1024);
    float* fwT     = (float*)(ws + 4864u * 1024);
    short* w2b     = (short*)(ws + 4992u * 1024);
    short* w1b     = (short*)(ws + 5136u * 1024);
    short* c1full  = (short*)(ws + 6144u * 1024);

    size_t avail = ws_size > (6u << 20) ? ws_size - (6u << 20) : 0;
    int ipp = 1024;
    while (ipp > 32 && (size_t)ipp * 131072ull > avail) ipp >>= 1;
    int npass = 1024 / ipp;

    prep_kernel<<<dim3(288), 256, 0, stream>>>(s1lw, s1rw, s2lw, s2rw, c2w, c1w, c1b,
                                               fcw, l1T, w1pT, l2T, w2pT, fwT, w2b, w1b);
    for (int p = 0; p < npass; ++p) {
        conv1_kernel<<<dim3(8, ipp), 256, 0, stream>>>(x, w1b, c1full, p * ipp);
        conv2_kernel<<<dim3(8, ipp), 256, 0, stream>>>(c1full, w2b, c2b, pooled8, p * ipp);
    }
    tail_kernel<<<dim3(32), 256, 0, stream>>>(pooled8, fwT, fcb, mask,
                                              l1T, s1lb, w1pT, l2T, s2lb, w2pT, out);
}

// Round 11
// 338.671 us; speedup vs baseline: 1.4094x; 1.4094x over previous
//
#include <hip/hip_runtime.h>
#include <hip/hip_bf16.h>

// x:[1024,3,32,32] -> conv1(3->64)+relu -> conv2(64->128)+relu -> meanpool
// -> fc(128->256)+b -> *mask -> sage1(256->256)+relu -> sage2(256->128)
// Output [32,32,128] fp32.
//
// Workspace layout:
//  [0,2M)        pooled4 [1024][4][128] f32 (band partials, pre-divide)
//  [2M,3M)       z1 [1024][256]
//  [3M,4M)       z2 [1024][256]
//  [4096K,+256K) l1T  [256][256] = s1lw^T
//  [4352K,+256K) w1pT [256][256] = (s1rw - s1lw/31)^T
//  [4608K,+128K) l2T  [256][128] = s2lw^T
//  [4736K,+128K) w2pT [256][128] = (s2rw - s2lw/31)^T
//  [4864K,+128K) fwT  [128][256] = fc_w^T
//  [4992K,+144K) w2b  [9][128][64] bf16 conv2 w, tap-major
//  [5136K,+4K)   w1b  [64][32] bf16 conv1 w+bias (k=27 slot = bias)
//  [6M, ...)     c1full chunk: imgs_per_pass x [32][32][64] bf16 (128KB/img)

typedef __attribute__((ext_vector_type(8))) short bfrag;
typedef __attribute__((ext_vector_type(4))) float f32x4;

static __device__ __forceinline__ unsigned short f2bf(float f) {
    union { float f; unsigned u; } v; v.f = f;
    unsigned r = v.u + 0x7fff + ((v.u >> 16) & 1);   // RNE (finite)
    return (unsigned short)(r >> 16);
}

__global__ __launch_bounds__(256) void prep_kernel(
    const float* __restrict__ s1lw, const float* __restrict__ s1rw,
    const float* __restrict__ s2lw, const float* __restrict__ s2rw,
    const float* __restrict__ c2w, const float* __restrict__ c1w,
    const float* __restrict__ c1b, const float* __restrict__ fcw,
    float* __restrict__ l1T, float* __restrict__ w1pT,
    float* __restrict__ l2T, float* __restrict__ w2pT,
    float* __restrict__ fwT,
    short* __restrict__ w2b, short* __restrict__ w1b) {
    int i = blockIdx.x * 256 + threadIdx.x;     // grid 288 -> [0, 73728)
    const float inv31 = 1.f / 31.f;
    if (i < 65536) {
        int d = i >> 8, o = i & 255;
        float lw = s1lw[o * 256 + d];
        l1T[i]  = lw;
        w1pT[i] = s1rw[o * 256 + d] - lw * inv31;
    }
    if (i < 32768) {
        int d = i >> 7, o = i & 127;
        float lw = s2lw[o * 256 + d];
        l2T[i]  = lw;
        w2pT[i] = s2rw[o * 256 + d] - lw * inv31;
        int c = i >> 8, o2 = i & 255;
        fwT[i] = fcw[o2 * 128 + c];
    }
    if (i < 73728) {                            // w2b[k][oc][ic] = c2w[oc][ic][k]
        int k = i >> 13, rem = i & 8191, oc = rem >> 6, ic = rem & 63;
        w2b[i] = (short)f2bf(c2w[(oc * 64 + ic) * 9 + k]);
    }
    if (i < 2048) {                             // w1b[oc][k], k=27 -> bias
        int oc = i >> 5, k = i & 31;
        float v = (k < 27) ? c1w[oc * 27 + k] : (k == 27 ? c1b[oc] : 0.f);
        w1b[i] = (short)f2bf(v);
    }
}

// conv1: grid (8 bands, imgs). One 4-row band per block; stage only 6 input rows.
__global__ __launch_bounds__(256, 4) void conv1_kernel(
    const float* __restrict__ x, const short* __restrict__ w1b,
    short* __restrict__ c1full, int img0) {
    const int band = blockIdx.x, limg = blockIdx.y, img = img0 + limg;
    __shared__ short xt[3 * 6 * 34];      // 1224 B: rows y0-1..y0+4, cols padded
    __shared__ short a1t[128 * 36];       // 9216 B im2col (K pad 36)
    __shared__ short c1band[4 * 32 * 64]; // 16384 B band output
    const int t = threadIdx.x;
    const int w = t >> 6, lane = t & 63;
    const int ln15 = lane & 15, q8 = (lane >> 4) * 8;
    const int y0 = band * 4;

    const float* xi = x + img * 3072;
    for (int idx = t; idx < 612; idx += 256) {
        int c = idx / 204, rem = idx % 204, r = rem / 34, col = rem % 34;
        int y = y0 + r - 1, xx = col - 1;
        float v = 0.f;
        if ((unsigned)y < 32u && (unsigned)xx < 32u) v = xi[c * 1024 + y * 32 + xx];
        xt[idx] = (short)f2bf(v);
    }
    bfrag b1f[4];
#pragma unroll
    for (int ot = 0; ot < 4; ++ot)
        b1f[ot] = *(const bfrag*)(w1b + (ot * 16 + ln15) * 32 + q8);
    __syncthreads();

    // im2col: 128 pos x 32 k; 2 threads per pos (k halves)
    {
        int p = t >> 1, r = p >> 5, xc = p & 31;
        short* ap = &a1t[p * 36];
        if ((t & 1) == 0) {
#pragma unroll
            for (int k = 0; k < 16; ++k) {
                int c = k / 9, rem = k - c * 9, dy = rem / 3, dx = rem - dy * 3;
                ap[k] = xt[c * 204 + (r + dy) * 34 + xc + dx];
            }
        } else {
#pragma unroll
            for (int k = 16; k < 27; ++k) {
                int c = k / 9, rem = k - c * 9, dy = rem / 3, dx = rem - dy * 3;
                ap[k] = xt[c * 204 + (r + dy) * 34 + xc + dx];
            }
            ap[27] = (short)0x3F80;              // 1.0 bias slot
            ap[28] = 0; ap[29] = 0; ap[30] = 0; ap[31] = 0;
        }
    }
    __syncthreads();
    // mfma: 8 pos-tiles of 16; wave w -> tiles 2w, 2w+1
#pragma unroll
    for (int pt = 0; pt < 2; ++pt) {
        const int tile = w * 2 + pt;
        bfrag a1f = *(const bfrag*)(&a1t[(tile * 16 + ln15) * 36 + q8]);
        f32x4 acc1[4];
#pragma unroll
        for (int ot = 0; ot < 4; ++ot) {
#pragma unroll
            for (int rg = 0; rg < 4; ++rg) acc1[ot][rg] = 0.f;
            acc1[ot] = __builtin_amdgcn_mfma_f32_16x16x32_bf16(
                a1f, b1f[ot], acc1[ot], 0, 0, 0);
        }
#pragma unroll
        for (int rg = 0; rg < 4; ++rg) {
            int pos = tile * 16 + (lane >> 4) * 4 + rg;   // 0..127
            int r = pos >> 5, xc = pos & 31;
#pragma unroll
            for (int ot = 0; ot < 4; ++ot)
                c1band[(r * 32 + xc) * 64 + ot * 16 + ln15] =
                    (short)f2bf(fmaxf(acc1[ot][rg], 0.f));
        }
    }
    __syncthreads();
    // copy band -> global (16384 B contiguous)
    {
        const f32x4* src = (const f32x4*)c1band;
        f32x4* dst = (f32x4*)(c1full + (size_t)limg * 65536 + band * 8192);
        for (int idx = t; idx < 1024; idx += 256) dst[idx] = src[idx];
    }
}

// conv2+pool: grid (4 bands of 8 rows, imgs). Wave = 128 pos x 64 oc, acc=128.
// launch_bounds(256,2): full reg budget needed (r8 lesson: a higher wave request
// shrinks the budget below the 128-acc live set -> accumulator spills -> 6x).
// r10 lesson: smaller tile (64 acc) halves B-load amortization -> slower even at
// 2x occupancy. This shape + 2-stage B pipeline is the measured optimum (178us).
__global__ __launch_bounds__(256, 2) void conv2_kernel(
    const short* __restrict__ c1full, const short* __restrict__ w2b,
    const float* __restrict__ b2, float* __restrict__ pooled4, int img0) {
    const int band = blockIdx.x, limg = blockIdx.y, img = img0 + limg;
    __shared__ short c1t[10 * 34 * 72];   // 48960 B [row][col pad34][ic pad72]
    __shared__ float wsum[4][64];
    const int t = threadIdx.x;
    const int w = t >> 6, lane = t & 63;
    const int ln15 = lane & 15, q8 = (lane >> 4) * 8;
    const int rg2 = w & 1, og = w >> 1;   // row-group (4 rows), oc-group (64 oc)

    {   // targeted zeroing: pad cols 0/33 (all rows) + OOB halo rows only.
        f32x4 z = {0.f, 0.f, 0.f, 0.f};
        for (int i = t; i < 180; i += 256) {          // 10r x 2c x 9 f32x4
            int r = i / 18, rem = i % 18, side = rem / 9, q = rem % 9;
            *(f32x4*)(c1t + (r * 34 + side * 33) * 72 + q * 8) = z;
        }
        if (band == 0)
            for (int i = t; i < 306; i += 256)        // row 0: 34 cols x 9
                *(f32x4*)(c1t + (0 * 34 + i / 9) * 72 + (i % 9) * 8) = z;
        if (band == 3)
            for (int i = t; i < 306; i += 256)        // row 9
                *(f32x4*)(c1t + (9 * 34 + i / 9) * 72 + (i % 9) * 8) = z;
    }
    {   // stage valid rows (disjoint from zeroed region -> no barrier between)
        const short* src = c1full + (size_t)limg * 65536;
        for (int idx = t; idx < 2560; idx += 256) {
            int row = idx >> 8, grow = band * 8 + row - 1;
            if ((unsigned)grow < 32u) {
                int c8 = idx & 255, col = c8 >> 3, q = c8 & 7;
                *(f32x4*)(c1t + (row * 34 + col + 1) * 72 + q * 8) =
                    *(const f32x4*)(src + (grow * 32 + col) * 64 + q * 8);
            }
        }
    }
    __syncthreads();

    float b2v[4];
#pragma unroll
    for (int ot = 0; ot < 4; ++ot) b2v[ot] = b2[og * 64 + ot * 16 + ln15];

    f32x4 acc[8][4];
#pragma unroll
    for (int pt = 0; pt < 8; ++pt)
#pragma unroll
        for (int ot = 0; ot < 4; ++ot)
#pragma unroll
            for (int rg = 0; rg < 4; ++rg) acc[pt][ot][rg] = 0.f;

    const short* wb0 = w2b + (og * 64 + ln15) * 64 + q8;
    auto loadB = [&](bfrag* dst, int tap) {
        const short* p = wb0 + tap * 8192;
#pragma unroll
        for (int kc = 0; kc < 2; ++kc)
#pragma unroll
            for (int ot = 0; ot < 4; ++ot)
                dst[kc * 4 + ot] = *(const bfrag*)(p + ot * 1024 + kc * 32);
    };
    auto compute = [&](const bfrag* bf, int tap) {
        const int dy = tap / 3, dx = tap - dy * 3;
#pragma unroll
        for (int kc = 0; kc < 2; ++kc)
#pragma unroll
            for (int pt = 0; pt < 8; ++pt) {
                int r = rg2 * 4 + (pt >> 1);
                int xc = ((pt & 1) << 4) + ln15;
                bfrag a2f = *(const bfrag*)(
                    &c1t[((r + dy) * 34 + xc + dx) * 72 + kc * 32 + q8]);
#pragma unroll
                for (int ot = 0; ot < 4; ++ot)
                    acc[pt][ot] = __builtin_amdgcn_mfma_f32_16x16x32_bf16(
                        a2f, bf[kc * 4 + ot], acc[pt][ot], 0, 0, 0);
            }
    };

    bfrag bA[8], bB[8];
    loadB(bA, 0);
#pragma unroll 1
    for (int tap = 0; tap < 9; tap += 2) {      // manual 2-stage pipeline
        if (tap + 1 < 9) loadB(bB, tap + 1);
        compute(bA, tap);
        if (tap + 2 < 9) loadB(bA, tap + 2);
        if (tap + 1 < 9) compute(bB, tap + 1);
    }

    // bias + relu + pool (wave covers 128 pos x 64 oc)
#pragma unroll
    for (int ot = 0; ot < 4; ++ot) {
        float s = 0.f;
#pragma unroll
        for (int pt = 0; pt < 8; ++pt)
#pragma unroll
            for (int rg = 0; rg < 4; ++rg)
                s += fmaxf(acc[pt][ot][rg] + b2v[ot], 0.f);
        s += __shfl_xor(s, 16, 64);
        s += __shfl_xor(s, 32, 64);
        if (lane < 16) wsum[w][ot * 16 + ln15] = s;
    }
    __syncthreads();
    if (t < 128) {
        int og2 = t >> 6, oo = t & 63;
        pooled4[((size_t)img * 4 + band) * 128 + t] =
            wsum[og2 * 2][oo] + wsum[og2 * 2 + 1][oo];
    }
}

// fc: grid 1024 (one block per image) -- wide grid hides weight-load latency.
__global__ __launch_bounds__(256) void fc_kernel(
    const float* __restrict__ pooled4, const float* __restrict__ fwT,
    const float* __restrict__ fb, const float* __restrict__ mask,
    float* __restrict__ z1) {
    const int img = blockIdx.x;
    __shared__ float m[128];
    const int t = threadIdx.x;
    if (t < 128) {
        const float* p = pooled4 + (size_t)img * 4 * 128 + t;
        m[t] = (p[0] + p[128] + p[256] + p[384]) * (1.f / 1024.f);
    }
    __syncthreads();
    float acc = fb[t];
#pragma unroll 4
    for (int c = 0; c < 128; ++c) acc = fmaf(m[c], fwT[c * 256 + t], acc);  // coalesced
    z1[img * 256 + t] = acc * mask[img];
}

// sage1+relu: grid 128 = (bb, chunk of 8 nodes); thread t = output o.
__global__ __launch_bounds__(256) void sage1_kernel(
    const float* __restrict__ z1, const float* __restrict__ l1T,
    const float* __restrict__ lb, const float* __restrict__ w1pT,
    float* __restrict__ z2) {
    const int bb = blockIdx.x >> 2, chunk = blockIdx.x & 3;
    __shared__ float h[32 * 256];
    __shared__ float sl[256];
    const int t = threadIdx.x;
    const float* zb = z1 + bb * 8192;
    for (int idx = t; idx < 8192; idx += 256) h[idx] = zb[idx];
    __syncthreads();
    float s = 0.f;
#pragma unroll
    for (int n = 0; n < 32; ++n) s += h[n * 256 + t];
    sl[t] = s * (1.f / 31.f);
    __syncthreads();
    float c = lb[t];
#pragma unroll 4
    for (int d = 0; d < 256; ++d) c = fmaf(sl[d], l1T[d * 256 + t], c);
    float acc[8];
#pragma unroll
    for (int i = 0; i < 8; ++i) acc[i] = c;
    for (int d0 = 0; d0 < 256; d0 += 4) {
        float wv0 = w1pT[(d0 + 0) * 256 + t];
        float wv1 = w1pT[(d0 + 1) * 256 + t];
        float wv2 = w1pT[(d0 + 2) * 256 + t];
        float wv3 = w1pT[(d0 + 3) * 256 + t];
#pragma unroll
        for (int i = 0; i < 8; ++i) {
            f32x4 hv = *(const f32x4*)&h[(chunk * 8 + i) * 256 + d0];  // LDS broadcast
            acc[i] = fmaf(hv[0], wv0, acc[i]);
            acc[i] = fmaf(hv[1], wv1, acc[i]);
            acc[i] = fmaf(hv[2], wv2, acc[i]);
            acc[i] = fmaf(hv[3], wv3, acc[i]);
        }
    }
    for (int i = 0; i < 8; ++i)
        z2[(bb * 32 + chunk * 8 + i) * 256 + t] = fmaxf(acc[i], 0.f);
}

// sage2: grid 128 = (bb, chunk of 8 nodes); o = t&127, half = t>>7 (4 nodes each).
__global__ __launch_bounds__(256) void sage2_kernel(
    const float* __restrict__ z2, const float* __restrict__ l2T,
    const float* __restrict__ lb, const float* __restrict__ w2pT,
    float* __restrict__ out) {
    const int bb = blockIdx.x >> 2, chunk = blockIdx.x & 3;
    __shared__ float h[32 * 256];
    __shared__ float sl[256];
    const int t = threadIdx.x;
    const float* zb = z2 + bb * 8192;
    for (int idx = t; idx < 8192; idx += 256) h[idx] = zb[idx];
    __syncthreads();
    float s = 0.f;
#pragma unroll
    for (int n = 0; n < 32; ++n) s += h[n * 256 + t];
    sl[t] = s * (1.f / 31.f);
    __syncthreads();
    const int o = t & 127, half = t >> 7;
    float c = lb[o];
#pragma unroll 4
    for (int d = 0; d < 256; ++d) c = fmaf(sl[d], l2T[d * 128 + o], c);
    float acc[4];
#pragma unroll
    for (int i = 0; i < 4; ++i) acc[i] = c;
    const int n0 = chunk * 8 + half * 4;
    for (int d0 = 0; d0 < 256; d0 += 4) {
        float wv0 = w2pT[(d0 + 0) * 128 + o];
        float wv1 = w2pT[(d0 + 1) * 128 + o];
        float wv2 = w2pT[(d0 + 2) * 128 + o];
        float wv3 = w2pT[(d0 + 3) * 128 + o];
#pragma unroll
        for (int ii = 0; ii < 4; ++ii) {
            f32x4 hv = *(const f32x4*)&h[(n0 + ii) * 256 + d0];
            acc[ii] = fmaf(hv[0], wv0, acc[ii]);
            acc[ii] = fmaf(hv[1], wv1, acc[ii]);
            acc[ii] = fmaf(hv[2], wv2, acc[ii]);
            acc[ii] = fmaf(hv[3], wv3, acc[ii]);
        }
    }
    for (int ii = 0; ii < 4; ++ii)
        out[(size_t)(bb * 32 + n0 + ii) * 128 + o] = acc[ii];
}

extern "C" void kernel_launch(void* const* d_in, const int* in_sizes, int n_in,
                              void* d_out, int out_size, void* d_ws, size_t ws_size,
                              hipStream_t stream) {
    const float* x    = (const float*)d_in[0];
    const float* mask = (const float*)d_in[1];
    const float* c1w  = (const float*)d_in[2];
    const float* c1b  = (const float*)d_in[3];
    const float* c2w  = (const float*)d_in[4];
    const float* c2b  = (const float*)d_in[5];
    const float* fcw  = (const float*)d_in[6];
    const float* fcb  = (const float*)d_in[7];
    const float* s1lw = (const float*)d_in[8];
    const float* s1lb = (const float*)d_in[9];
    const float* s1rw = (const float*)d_in[10];
    const float* s2lw = (const float*)d_in[11];
    const float* s2lb = (const float*)d_in[12];
    const float* s2rw = (const float*)d_in[13];
    float* out = (float*)d_out;

    char* ws = (char*)d_ws;
    float* pooled4 = (float*)(ws);
    float* z1      = (float*)(ws + 2048u * 1024);
    float* z2      = (float*)(ws + 3072u * 1024);
    float* l1T     = (float*)(ws + 4096u * 1024);
    float* w1pT    = (float*)(ws + 4352u * 1024);
    float* l2T     = (float*)(ws + 4608u * 1024);
    float* w2pT    = (float*)(ws + 4736u * 1024);
    float* fwT     = (float*)(ws + 4864u * 1024);
    short* w2b     = (short*)(ws + 4992u * 1024);
    short* w1b     = (short*)(ws + 5136u * 1024);
    short* c1full  = (short*)(ws + 6144u * 1024);

    size_t avail = ws_size > (6u << 20) ? ws_size - (6u << 20) : 0;
    int ipp = 1024;
    while (ipp > 32 && (size_t)ipp * 131072ull > avail) ipp >>= 1;
    int npass = 1024 / ipp;

    prep_kernel<<<dim3(288), 256, 0, stream>>>(s1lw, s1rw, s2lw, s2rw, c2w, c1w, c1b,
                                               fcw, l1T, w1pT, l2T, w2pT, fwT, w2b, w1b);
    for (int p = 0; p < npass; ++p) {
        conv1_kernel<<<dim3(8, ipp), 256, 0, stream>>>(x, w1b, c1full, p * ipp);
        conv2_kernel<<<dim3(4, ipp), 256, 0, stream>>>(c1full, w2b, c2b, pooled4, p * ipp);
    }
    fc_kernel<<<dim3(1024), 256, 0, stream>>>(pooled4, fwT, fcb, mask, z1);
    sage1_kernel<<<dim3(128), 256, 0, stream>>>(z1, l1T, s1lb, w1pT, z2);
    sage2_kernel<<<dim3(128), 256, 0, stream>>>(z2, l2T, s2lb, w2pT, out);
}

// Round 12
// 315.903 us; speedup vs baseline: 1.5110x; 1.0721x over previous
//
#include <hip/hip_runtime.h>
#include <hip/hip_bf16.h>

// x:[1024,3,32,32] -> conv1(3->64)+relu -> conv2(64->128)+relu -> meanpool
// -> fc(128->256)+b -> *mask -> sage1(256->256)+relu -> sage2(256->128)
// Output [32,32,128] fp32.
//
// Workspace layout (<6MB, no conv1 intermediate):
//  [0,2M)        pooled4 [1024][4][128] f32 (band partials, pre-divide)
//  [2M,3M)       z1 [1024][256]
//  [3M,4M)       z2 [1024][256]
//  [4096K,+256K) l1T  [256][256] = s1lw^T
//  [4352K,+256K) w1pT [256][256] = (s1rw - s1lw/31)^T
//  [4608K,+128K) l2T  [256][128] = s2lw^T
//  [4736K,+128K) w2pT [256][128] = (s2rw - s2lw/31)^T
//  [4864K,+128K) fwT  [128][256] = fc_w^T
//  [4992K,+144K) w2b  [9][128][64] bf16 conv2 w, tap-major
//  [5136K,+4K)   w1b  [64][32] bf16 conv1 w+bias (k=27 slot = bias)

typedef __attribute__((ext_vector_type(8))) short bfrag;
typedef __attribute__((ext_vector_type(4))) float f32x4;

static __device__ __forceinline__ unsigned short f2bf(float f) {
    union { float f; unsigned u; } v; v.f = f;
    unsigned r = v.u + 0x7fff + ((v.u >> 16) & 1);   // RNE (finite)
    return (unsigned short)(r >> 16);
}

__global__ __launch_bounds__(256) void prep_kernel(
    const float* __restrict__ s1lw, const float* __restrict__ s1rw,
    const float* __restrict__ s2lw, const float* __restrict__ s2rw,
    const float* __restrict__ c2w, const float* __restrict__ c1w,
    const float* __restrict__ c1b, const float* __restrict__ fcw,
    float* __restrict__ l1T, float* __restrict__ w1pT,
    float* __restrict__ l2T, float* __restrict__ w2pT,
    float* __restrict__ fwT,
    short* __restrict__ w2b, short* __restrict__ w1b) {
    int i = blockIdx.x * 256 + threadIdx.x;     // grid 288 -> [0, 73728)
    const float inv31 = 1.f / 31.f;
    if (i < 65536) {
        int d = i >> 8, o = i & 255;
        float lw = s1lw[o * 256 + d];
        l1T[i]  = lw;
        w1pT[i] = s1rw[o * 256 + d] - lw * inv31;
    }
    if (i < 32768) {
        int d = i >> 7, o = i & 127;
        float lw = s2lw[o * 256 + d];
        l2T[i]  = lw;
        w2pT[i] = s2rw[o * 256 + d] - lw * inv31;
        int c = i >> 8, o2 = i & 255;
        fwT[i] = fcw[o2 * 128 + c];
    }
    if (i < 73728) {                            // w2b[k][oc][ic] = c2w[oc][ic][k]
        int k = i >> 13, rem = i & 8191, oc = rem >> 6, ic = rem & 63;
        w2b[i] = (short)f2bf(c2w[(oc * 64 + ic) * 9 + k]);
    }
    if (i < 2048) {                             // w1b[oc][k], k=27 -> bias
        int oc = i >> 5, k = i & 31;
        float v = (k < 27) ? c1w[oc * 27 + k] : (k == 27 ? c1b[oc] : 0.f);
        w1b[i] = (short)f2bf(v);
    }
}

// Fused conv1+conv2+pool: grid (4 bands of 8 rows, 1024 imgs).
// Phase A: conv1 for the 10 c1t rows this band needs (direct-from-xt fragment
//   assembly, no im2col buffer; ~80 MFMA/block = ~3% of block).
// Phase B: pipelined conv2, wave = 128 pos x 64 oc, acc=128 (the measured
//   optimum; r8 lesson: (256,2) only — higher wave request spills the acc;
//   r10 lesson: smaller tiles halve B amortization and lose).
__global__ __launch_bounds__(256, 2) void fused_conv_kernel(
    const float* __restrict__ x, const short* __restrict__ w1b,
    const short* __restrict__ w2b, const float* __restrict__ b2,
    float* __restrict__ pooled4) {
    const int band = blockIdx.x, img = blockIdx.y;
    __shared__ short xt[3 * 12 * 34];     // 2448 B: input rows band*8-2..band*8+9
    __shared__ short c1t[10 * 34 * 72];   // 48960 B [row][col pad34][ic pad72]
    __shared__ float wsum[4][64];
    const int t = threadIdx.x;
    const int w = t >> 6, lane = t & 63;
    const int ln15 = lane & 15, q8 = (lane >> 4) * 8;
    const int rg2 = w & 1, og = w >> 1;   // phase-B row-group / oc-group

    // stage xt (zero-padded), zero c1t pad cols 0/33
    const float* xi = x + img * 3072;
    for (int idx = t; idx < 1224; idx += 256) {
        int c = idx / 408, rem = idx % 408, r = rem / 34, col = rem % 34;
        int y = band * 8 - 2 + r, xx = col - 1;
        float v = 0.f;
        if ((unsigned)y < 32u && (unsigned)xx < 32u) v = xi[c * 1024 + y * 32 + xx];
        xt[idx] = (short)f2bf(v);
    }
    {
        f32x4 z = {0.f, 0.f, 0.f, 0.f};
        for (int i = t; i < 180; i += 256) {          // 10r x 2c x 9 f32x4
            int r = i / 18, rem = i % 18, side = rem / 9, q = rem % 9;
            *(f32x4*)(c1t + (r * 34 + side * 33) * 72 + q * 8) = z;
        }
    }
    bfrag b1f[4];
#pragma unroll
    for (int ot = 0; ot < 4; ++ot)
        b1f[ot] = *(const bfrag*)(w1b + (ot * 16 + ln15) * 32 + q8);
    __syncthreads();

    // ---- phase A: conv1 -> c1t. 20 pos-tiles of 16 (10 rows x 32 cols);
    //      wave w -> tiles 5w..5w+4. A-frag assembled straight from xt. ----
#pragma unroll 1
    for (int pt = 0; pt < 5; ++pt) {
        const int tile = w * 5 + pt;
        // A[m=ln15][k=q8+j]: pos = tile*16+ln15; k -> (c,dy,dx)
        const int posA = tile * 16 + ln15;
        const int baseA = (posA >> 5) * 34 + (posA & 31);
        bfrag a1f;
#pragma unroll
        for (int j = 0; j < 8; ++j) {
            int k = q8 + j;
            int c = (k * 57) >> 9;               // k/9 for k<36
            int rem = k - 9 * c;
            int dy = (rem * 11) >> 5;            // rem/3 for rem<9
            int dx = rem - 3 * dy;
            int cc = c < 3 ? c : 2;              // clamp for safe read
            short v = xt[cc * 408 + baseA + dy * 34 + dx];
            if (c >= 3) v = (k == 27) ? (short)0x3F80 : (short)0;  // bias / zero
            a1f[j] = v;
        }
        f32x4 acc1[4];
#pragma unroll
        for (int ot = 0; ot < 4; ++ot) {
#pragma unroll
            for (int rg = 0; rg < 4; ++rg) acc1[ot][rg] = 0.f;
            acc1[ot] = __builtin_amdgcn_mfma_f32_16x16x32_bf16(
                a1f, b1f[ot], acc1[ot], 0, 0, 0);
        }
        // D[col=ln15=oc][row=(lane>>4)*4+rg=pos]; mask SAME-pad rows -> 0
#pragma unroll
        for (int rg = 0; rg < 4; ++rg) {
            int pos = tile * 16 + (lane >> 4) * 4 + rg;  // 0..319
            int r = pos >> 5, xc = pos & 31;
            int y = band * 8 - 1 + r;
            bool valid = (unsigned)y < 32u;
#pragma unroll
            for (int ot = 0; ot < 4; ++ot) {
                float v = fmaxf(acc1[ot][rg], 0.f);
                c1t[(r * 34 + xc + 1) * 72 + ot * 16 + ln15] =
                    valid ? (short)f2bf(v) : (short)0;
            }
        }
    }
    __syncthreads();

    // ---- phase B: pipelined conv2 (identical to the 174us kernel) ----
    float b2v[4];
#pragma unroll
    for (int ot = 0; ot < 4; ++ot) b2v[ot] = b2[og * 64 + ot * 16 + ln15];

    f32x4 acc[8][4];
#pragma unroll
    for (int pt = 0; pt < 8; ++pt)
#pragma unroll
        for (int ot = 0; ot < 4; ++ot)
#pragma unroll
            for (int rg = 0; rg < 4; ++rg) acc[pt][ot][rg] = 0.f;

    const short* wb0 = w2b + (og * 64 + ln15) * 64 + q8;
    auto loadB = [&](bfrag* dst, int tap) {
        const short* p = wb0 + tap * 8192;
#pragma unroll
        for (int kc = 0; kc < 2; ++kc)
#pragma unroll
            for (int ot = 0; ot < 4; ++ot)
                dst[kc * 4 + ot] = *(const bfrag*)(p + ot * 1024 + kc * 32);
    };
    auto compute = [&](const bfrag* bf, int tap) {
        const int dy = tap / 3, dx = tap - dy * 3;
#pragma unroll
        for (int kc = 0; kc < 2; ++kc)
#pragma unroll
            for (int pt = 0; pt < 8; ++pt) {
                int r = rg2 * 4 + (pt >> 1);
                int xc = ((pt & 1) << 4) + ln15;
                bfrag a2f = *(const bfrag*)(
                    &c1t[((r + dy) * 34 + xc + dx) * 72 + kc * 32 + q8]);
#pragma unroll
                for (int ot = 0; ot < 4; ++ot)
                    acc[pt][ot] = __builtin_amdgcn_mfma_f32_16x16x32_bf16(
                        a2f, bf[kc * 4 + ot], acc[pt][ot], 0, 0, 0);
            }
    };

    bfrag bA[8], bB[8];
    loadB(bA, 0);
#pragma unroll 1
    for (int tap = 0; tap < 9; tap += 2) {      // manual 2-stage pipeline
        if (tap + 1 < 9) loadB(bB, tap + 1);
        compute(bA, tap);
        if (tap + 2 < 9) loadB(bA, tap + 2);
        if (tap + 1 < 9) compute(bB, tap + 1);
    }

    // bias + relu + pool (wave covers 128 pos x 64 oc)
#pragma unroll
    for (int ot = 0; ot < 4; ++ot) {
        float s = 0.f;
#pragma unroll
        for (int pt = 0; pt < 8; ++pt)
#pragma unroll
            for (int rg = 0; rg < 4; ++rg)
                s += fmaxf(acc[pt][ot][rg] + b2v[ot], 0.f);
        s += __shfl_xor(s, 16, 64);
        s += __shfl_xor(s, 32, 64);
        if (lane < 16) wsum[w][ot * 16 + ln15] = s;
    }
    __syncthreads();
    if (t < 128) {
        int og2 = t >> 6, oo = t & 63;
        pooled4[((size_t)img * 4 + band) * 128 + t] =
            wsum[og2 * 2][oo] + wsum[og2 * 2 + 1][oo];
    }
}

// fc: grid 1024 (one block per image) -- wide grid hides weight-load latency.
__global__ __launch_bounds__(256) void fc_kernel(
    const float* __restrict__ pooled4, const float* __restrict__ fwT,
    const float* __restrict__ fb, const float* __restrict__ mask,
    float* __restrict__ z1) {
    const int img = blockIdx.x;
    __shared__ float m[128];
    const int t = threadIdx.x;
    if (t < 128) {
        const float* p = pooled4 + (size_t)img * 4 * 128 + t;
        m[t] = (p[0] + p[128] + p[256] + p[384]) * (1.f / 1024.f);
    }
    __syncthreads();
    float acc = fb[t];
#pragma unroll 4
    for (int c = 0; c < 128; ++c) acc = fmaf(m[c], fwT[c * 256 + t], acc);  // coalesced
    z1[img * 256 + t] = acc * mask[img];
}

// sage1+relu: grid 128 = (bb, chunk of 8 nodes); thread t = output o.
__global__ __launch_bounds__(256) void sage1_kernel(
    const float* __restrict__ z1, const float* __restrict__ l1T,
    const float* __restrict__ lb, const float* __restrict__ w1pT,
    float* __restrict__ z2) {
    const int bb = blockIdx.x >> 2, chunk = blockIdx.x & 3;
    __shared__ float h[32 * 256];
    __shared__ float sl[256];
    const int t = threadIdx.x;
    const float* zb = z1 + bb * 8192;
    for (int idx = t; idx < 8192; idx += 256) h[idx] = zb[idx];
    __syncthreads();
    float s = 0.f;
#pragma unroll
    for (int n = 0; n < 32; ++n) s += h[n * 256 + t];
    sl[t] = s * (1.f / 31.f);
    __syncthreads();
    float c = lb[t];
#pragma unroll 4
    for (int d = 0; d < 256; ++d) c = fmaf(sl[d], l1T[d * 256 + t], c);
    float acc[8];
#pragma unroll
    for (int i = 0; i < 8; ++i) acc[i] = c;
    for (int d0 = 0; d0 < 256; d0 += 4) {
        float wv0 = w1pT[(d0 + 0) * 256 + t];
        float wv1 = w1pT[(d0 + 1) * 256 + t];
        float wv2 = w1pT[(d0 + 2) * 256 + t];
        float wv3 = w1pT[(d0 + 3) * 256 + t];
#pragma unroll
        for (int i = 0; i < 8; ++i) {
            f32x4 hv = *(const f32x4*)&h[(chunk * 8 + i) * 256 + d0];  // LDS broadcast
            acc[i] = fmaf(hv[0], wv0, acc[i]);
            acc[i] = fmaf(hv[1], wv1, acc[i]);
            acc[i] = fmaf(hv[2], wv2, acc[i]);
            acc[i] = fmaf(hv[3], wv3, acc[i]);
        }
    }
    for (int i = 0; i < 8; ++i)
        z2[(bb * 32 + chunk * 8 + i) * 256 + t] = fmaxf(acc[i], 0.f);
}

// sage2: grid 128 = (bb, chunk of 8 nodes); o = t&127, half = t>>7 (4 nodes each).
__global__ __launch_bounds__(256) void sage2_kernel(
    const float* __restrict__ z2, const float* __restrict__ l2T,
    const float* __restrict__ lb, const float* __restrict__ w2pT,
    float* __restrict__ out) {
    const int bb = blockIdx.x >> 2, chunk = blockIdx.x & 3;
    __shared__ float h[32 * 256];
    __shared__ float sl[256];
    const int t = threadIdx.x;
    const float* zb = z2 + bb * 8192;
    for (int idx = t; idx < 8192; idx += 256) h[idx] = zb[idx];
    __syncthreads();
    float s = 0.f;
#pragma unroll
    for (int n = 0; n < 32; ++n) s += h[n * 256 + t];
    sl[t] = s * (1.f / 31.f);
    __syncthreads();
    const int o = t & 127, half = t >> 7;
    float c = lb[o];
#pragma unroll 4
    for (int d = 0; d < 256; ++d) c = fmaf(sl[d], l2T[d * 128 + o], c);
    float acc[4];
#pragma unroll
    for (int i = 0; i < 4; ++i) acc[i] = c;
    const int n0 = chunk * 8 + half * 4;
    for (int d0 = 0; d0 < 256; d0 += 4) {
        float wv0 = w2pT[(d0 + 0) * 128 + o];
        float wv1 = w2pT[(d0 + 1) * 128 + o];
        float wv2 = w2pT[(d0 + 2) * 128 + o];
        float wv3 = w2pT[(d0 + 3) * 128 + o];
#pragma unroll
        for (int ii = 0; ii < 4; ++ii) {
            f32x4 hv = *(const f32x4*)&h[(n0 + ii) * 256 + d0];
            acc[ii] = fmaf(hv[0], wv0, acc[ii]);
            acc[ii] = fmaf(hv[1], wv1, acc[ii]);
            acc[ii] = fmaf(hv[2], wv2, acc[ii]);
            acc[ii] = fmaf(hv[3], wv3, acc[ii]);
        }
    }
    for (int ii = 0; ii < 4; ++ii)
        out[(size_t)(bb * 32 + n0 + ii) * 128 + o] = acc[ii];
}

extern "C" void kernel_launch(void* const* d_in, const int* in_sizes, int n_in,
                              void* d_out, int out_size, void* d_ws, size_t ws_size,
                              hipStream_t stream) {
    const float* x    = (const float*)d_in[0];
    const float* mask = (const float*)d_in[1];
    const float* c1w  = (const float*)d_in[2];
    const float* c1b  = (const float*)d_in[3];
    const float* c2w  = (const float*)d_in[4];
    const float* c2b  = (const float*)d_in[5];
    const float* fcw  = (const float*)d_in[6];
    const float* fcb  = (const float*)d_in[7];
    const float* s1lw = (const float*)d_in[8];
    const float* s1lb = (const float*)d_in[9];
    const float* s1rw = (const float*)d_in[10];
    const float* s2lw = (const float*)d_in[11];
    const float* s2lb = (const float*)d_in[12];
    const float* s2rw = (const float*)d_in[13];
    float* out = (float*)d_out;

    char* ws = (char*)d_ws;
    float* pooled4 = (float*)(ws);
    float* z1      = (float*)(ws + 2048u * 1024);
    float* z2      = (float*)(ws + 3072u * 1024);
    float* l1T     = (float*)(ws + 4096u * 1024);
    float* w1pT    = (float*)(ws + 4352u * 1024);
    float* l2T     = (float*)(ws + 4608u * 1024);
    float* w2pT    = (float*)(ws + 4736u * 1024);
    float* fwT     = (float*)(ws + 4864u * 1024);
    short* w2b     = (short*)(ws + 4992u * 1024);
    short* w1b     = (short*)(ws + 5136u * 1024);

    prep_kernel<<<dim3(288), 256, 0, stream>>>(s1lw, s1rw, s2lw, s2rw, c2w, c1w, c1b,
                                               fcw, l1T, w1pT, l2T, w2pT, fwT, w2b, w1b);
    fused_conv_kernel<<<dim3(4, 1024), 256, 0, stream>>>(x, w1b, w2b, c2b, pooled4);
    fc_kernel<<<dim3(1024), 256, 0, stream>>>(pooled4, fwT, fcb, mask, z1);
    sage1_kernel<<<dim3(128), 256, 0, stream>>>(z1, l1T, s1lb, w1pT, z2);
    sage2_kernel<<<dim3(128), 256, 0, stream>>>(z2, l2T, s2lb, w2pT, out);
}

// Round 13
// 309.846 us; speedup vs baseline: 1.5405x; 1.0196x over previous
//
#include <hip/hip_runtime.h>
#include <hip/hip_bf16.h>

// x:[1024,3,32,32] -> conv1(3->64)+relu -> conv2(64->128)+relu -> meanpool
// -> fc(128->256)+b -> *mask -> sage1(256->256)+relu -> sage2(256->128)
// Output [32,32,128] fp32.
//
// Workspace layout (<6MB, no conv1 intermediate):
//  [0,2M)        pooled4 [1024][4][128] f32 (band partials, pre-divide)
//  [2M,3M)       z1 [1024][256]
//  [3M,4M)       z2 [1024][256]
//  [4096K,+256K) l1T  [256][256] = s1lw^T
//  [4352K,+256K) w1pT [256][256] = (s1rw - s1lw/31)^T
//  [4608K,+128K) l2T  [256][128] = s2lw^T
//  [4736K,+128K) w2pT [256][128] = (s2rw - s2lw/31)^T
//  [4864K,+128K) fwT  [128][256] = fc_w^T
//  [4992K,+144K) w2b  [9][128][64] bf16 conv2 w, tap-major
//  [5136K,+4K)   w1b  [64][32] bf16 conv1 w+bias (k=27 slot = bias)

typedef __attribute__((ext_vector_type(8))) short bfrag;
typedef __attribute__((ext_vector_type(4))) float f32x4;

static __device__ __forceinline__ unsigned short f2bf(float f) {
    union { float f; unsigned u; } v; v.f = f;
    unsigned r = v.u + 0x7fff + ((v.u >> 16) & 1);   // RNE (finite)
    return (unsigned short)(r >> 16);
}

__global__ __launch_bounds__(256) void prep_kernel(
    const float* __restrict__ s1lw, const float* __restrict__ s1rw,
    const float* __restrict__ s2lw, const float* __restrict__ s2rw,
    const float* __restrict__ c2w, const float* __restrict__ c1w,
    const float* __restrict__ c1b, const float* __restrict__ fcw,
    float* __restrict__ l1T, float* __restrict__ w1pT,
    float* __restrict__ l2T, float* __restrict__ w2pT,
    float* __restrict__ fwT,
    short* __restrict__ w2b, short* __restrict__ w1b) {
    int i = blockIdx.x * 256 + threadIdx.x;     // grid 288 -> [0, 73728)
    const float inv31 = 1.f / 31.f;
    if (i < 65536) {
        int d = i >> 8, o = i & 255;
        float lw = s1lw[o * 256 + d];
        l1T[i]  = lw;
        w1pT[i] = s1rw[o * 256 + d] - lw * inv31;
    }
    if (i < 32768) {
        int d = i >> 7, o = i & 127;
        float lw = s2lw[o * 256 + d];
        l2T[i]  = lw;
        w2pT[i] = s2rw[o * 256 + d] - lw * inv31;
        int c = i >> 8, o2 = i & 255;
        fwT[i] = fcw[o2 * 128 + c];
    }
    if (i < 73728) {                            // w2b[k][oc][ic] = c2w[oc][ic][k]
        int k = i >> 13, rem = i & 8191, oc = rem >> 6, ic = rem & 63;
        w2b[i] = (short)f2bf(c2w[(oc * 64 + ic) * 9 + k]);
    }
    if (i < 2048) {                             // w1b[oc][k], k=27 -> bias
        int oc = i >> 5, k = i & 31;
        float v = (k < 27) ? c1w[oc * 27 + k] : (k == 27 ? c1b[oc] : 0.f);
        w1b[i] = (short)f2bf(v);
    }
}

// Fused conv1+conv2+pool: grid (4 bands of 8 rows, 1024 imgs).
// Phase A: conv1 for the 10 c1t rows this band needs (direct-from-xt fragment
//   assembly). Phase B: pipelined conv2, wave = 128 pos x 64 oc, acc=128.
// r8: (256,2) only — higher wave request spills the acc. r10: smaller tiles
// halve B amortization and lose. r13: per-pt LDS base addresses hoisted out of
// the tap loop (tap-uniform delta goes to SALU) to cut hot-loop VALU.
__global__ __launch_bounds__(256, 2) void fused_conv_kernel(
    const float* __restrict__ x, const short* __restrict__ w1b,
    const short* __restrict__ w2b, const float* __restrict__ b2,
    float* __restrict__ pooled4) {
    const int band = blockIdx.x, img = blockIdx.y;
    __shared__ short xt[3 * 12 * 34];     // 2448 B: input rows band*8-2..band*8+9
    __shared__ short c1t[10 * 34 * 72];   // 48960 B [row][col pad34][ic pad72]
    __shared__ float wsum[4][64];
    const int t = threadIdx.x;
    const int w = t >> 6, lane = t & 63;
    const int ln15 = lane & 15, q8 = (lane >> 4) * 8;
    const int rg2 = w & 1, og = w >> 1;   // phase-B row-group / oc-group

    // stage xt (zero-padded), zero c1t pad cols 0/33
    const float* xi = x + img * 3072;
    for (int idx = t; idx < 1224; idx += 256) {
        int c = idx / 408, rem = idx % 408, r = rem / 34, col = rem % 34;
        int y = band * 8 - 2 + r, xx = col - 1;
        float v = 0.f;
        if ((unsigned)y < 32u && (unsigned)xx < 32u) v = xi[c * 1024 + y * 32 + xx];
        xt[idx] = (short)f2bf(v);
    }
    {
        f32x4 z = {0.f, 0.f, 0.f, 0.f};
        for (int i = t; i < 180; i += 256) {          // 10r x 2c x 9 f32x4
            int r = i / 18, rem = i % 18, side = rem / 9, q = rem % 9;
            *(f32x4*)(c1t + (r * 34 + side * 33) * 72 + q * 8) = z;
        }
    }
    bfrag b1f[4];
#pragma unroll
    for (int ot = 0; ot < 4; ++ot)
        b1f[ot] = *(const bfrag*)(w1b + (ot * 16 + ln15) * 32 + q8);
    __syncthreads();

    // ---- phase A: conv1 -> c1t. 20 pos-tiles of 16 (10 rows x 32 cols);
    //      wave w -> tiles 5w..5w+4. A-frag assembled straight from xt. ----
#pragma unroll 1
    for (int pt = 0; pt < 5; ++pt) {
        const int tile = w * 5 + pt;
        const int posA = tile * 16 + ln15;
        const int baseA = (posA >> 5) * 34 + (posA & 31);
        bfrag a1f;
#pragma unroll
        for (int j = 0; j < 8; ++j) {
            int k = q8 + j;
            int c = (k * 57) >> 9;               // k/9 for k<36
            int rem = k - 9 * c;
            int dy = (rem * 11) >> 5;            // rem/3 for rem<9
            int dx = rem - 3 * dy;
            int cc = c < 3 ? c : 2;              // clamp for safe read
            short v = xt[cc * 408 + baseA + dy * 34 + dx];
            if (c >= 3) v = (k == 27) ? (short)0x3F80 : (short)0;  // bias / zero
            a1f[j] = v;
        }
        f32x4 acc1[4];
#pragma unroll
        for (int ot = 0; ot < 4; ++ot) {
#pragma unroll
            for (int rg = 0; rg < 4; ++rg) acc1[ot][rg] = 0.f;
            acc1[ot] = __builtin_amdgcn_mfma_f32_16x16x32_bf16(
                a1f, b1f[ot], acc1[ot], 0, 0, 0);
        }
#pragma unroll
        for (int rg = 0; rg < 4; ++rg) {
            int pos = tile * 16 + (lane >> 4) * 4 + rg;  // 0..319
            int r = pos >> 5, xc = pos & 31;
            int y = band * 8 - 1 + r;
            bool valid = (unsigned)y < 32u;
#pragma unroll
            for (int ot = 0; ot < 4; ++ot) {
                float v = fmaxf(acc1[ot][rg], 0.f);
                c1t[(r * 34 + xc + 1) * 72 + ot * 16 + ln15] =
                    valid ? (short)f2bf(v) : (short)0;
            }
        }
    }
    __syncthreads();

    // ---- phase B: pipelined conv2 ----
    float b2v[4];
#pragma unroll
    for (int ot = 0; ot < 4; ++ot) b2v[ot] = b2[og * 64 + ot * 16 + ln15];

    f32x4 acc[8][4];
#pragma unroll
    for (int pt = 0; pt < 8; ++pt)
#pragma unroll
        for (int ot = 0; ot < 4; ++ot)
#pragma unroll
            for (int rg = 0; rg < 4; ++rg) acc[pt][ot][rg] = 0.f;

    // hoisted per-pt LDS element bases (loop-invariant over taps)
    int aBase[8];
#pragma unroll
    for (int pt = 0; pt < 8; ++pt) {
        int r = rg2 * 4 + (pt >> 1);
        int xc = ((pt & 1) << 4) + ln15;
        aBase[pt] = (r * 34 + xc) * 72 + q8;
    }

    const short* wb0 = w2b + (og * 64 + ln15) * 64 + q8;
    auto loadB = [&](bfrag* dst, int tap) {
        const short* p = wb0 + tap * 8192;
#pragma unroll
        for (int kc = 0; kc < 2; ++kc)
#pragma unroll
            for (int ot = 0; ot < 4; ++ot)
                dst[kc * 4 + ot] = *(const bfrag*)(p + ot * 1024 + kc * 32);
    };
    auto compute = [&](const bfrag* bf, int tap) {
        const int dy = tap / 3, dx = tap - dy * 3;
        const int dOff = (dy * 34 + dx) * 72;          // wave-uniform -> SALU
#pragma unroll
        for (int pt = 0; pt < 8; ++pt) {
            const int a0 = aBase[pt] + dOff;           // 1 v_add per pt
#pragma unroll
            for (int kc = 0; kc < 2; ++kc) {
                bfrag a2f = *(const bfrag*)(&c1t[a0 + kc * 32]);  // imm offset
#pragma unroll
                for (int ot = 0; ot < 4; ++ot)
                    acc[pt][ot] = __builtin_amdgcn_mfma_f32_16x16x32_bf16(
                        a2f, bf[kc * 4 + ot], acc[pt][ot], 0, 0, 0);
            }
        }
    };

    bfrag bA[8], bB[8];
    loadB(bA, 0);
#pragma unroll 1
    for (int tap = 0; tap < 9; tap += 2) {      // manual 2-stage pipeline
        if (tap + 1 < 9) loadB(bB, tap + 1);
        compute(bA, tap);
        if (tap + 2 < 9) loadB(bA, tap + 2);
        if (tap + 1 < 9) compute(bB, tap + 1);
    }

    // bias + relu + pool (wave covers 128 pos x 64 oc)
#pragma unroll
    for (int ot = 0; ot < 4; ++ot) {
        float s = 0.f;
#pragma unroll
        for (int pt = 0; pt < 8; ++pt)
#pragma unroll
            for (int rg = 0; rg < 4; ++rg)
                s += fmaxf(acc[pt][ot][rg] + b2v[ot], 0.f);
        s += __shfl_xor(s, 16, 64);
        s += __shfl_xor(s, 32, 64);
        if (lane < 16) wsum[w][ot * 16 + ln15] = s;
    }
    __syncthreads();
    if (t < 128) {
        int og2 = t >> 6, oo = t & 63;
        pooled4[((size_t)img * 4 + band) * 128 + t] =
            wsum[og2 * 2][oo] + wsum[og2 * 2 + 1][oo];
    }
}

// fc: grid 1024 (one block per image) -- wide grid hides weight-load latency.
__global__ __launch_bounds__(256) void fc_kernel(
    const float* __restrict__ pooled4, const float* __restrict__ fwT,
    const float* __restrict__ fb, const float* __restrict__ mask,
    float* __restrict__ z1) {
    const int img = blockIdx.x;
    __shared__ float m[128];
    const int t = threadIdx.x;
    if (t < 128) {
        const float* p = pooled4 + (size_t)img * 4 * 128 + t;
        m[t] = (p[0] + p[128] + p[256] + p[384]) * (1.f / 1024.f);
    }
    __syncthreads();
    float acc = fb[t];
#pragma unroll 4
    for (int c = 0; c < 128; ++c) acc = fmaf(m[c], fwT[c * 256 + t], acc);  // coalesced
    z1[img * 256 + t] = acc * mask[img];
}

// sage1+relu: grid 256 = (bb, chunk of 4 nodes); thread t = output o.
__global__ __launch_bounds__(256) void sage1_kernel(
    const float* __restrict__ z1, const float* __restrict__ l1T,
    const float* __restrict__ lb, const float* __restrict__ w1pT,
    float* __restrict__ z2) {
    const int bb = blockIdx.x >> 3, chunk = blockIdx.x & 7;
    __shared__ float h[32 * 256];
    __shared__ float sl[256];
    const int t = threadIdx.x;
    const float* zb = z1 + bb * 8192;
    for (int idx = t; idx < 8192; idx += 256) h[idx] = zb[idx];
    __syncthreads();
    float s = 0.f;
#pragma unroll
    for (int n = 0; n < 32; ++n) s += h[n * 256 + t];
    sl[t] = s * (1.f / 31.f);
    __syncthreads();
    float c = lb[t];
#pragma unroll 4
    for (int d = 0; d < 256; ++d) c = fmaf(sl[d], l1T[d * 256 + t], c);
    float acc[4];
#pragma unroll
    for (int i = 0; i < 4; ++i) acc[i] = c;
    for (int d0 = 0; d0 < 256; d0 += 4) {
        float wv0 = w1pT[(d0 + 0) * 256 + t];
        float wv1 = w1pT[(d0 + 1) * 256 + t];
        float wv2 = w1pT[(d0 + 2) * 256 + t];
        float wv3 = w1pT[(d0 + 3) * 256 + t];
#pragma unroll
        for (int i = 0; i < 4; ++i) {
            f32x4 hv = *(const f32x4*)&h[(chunk * 4 + i) * 256 + d0];  // LDS broadcast
            acc[i] = fmaf(hv[0], wv0, acc[i]);
            acc[i] = fmaf(hv[1], wv1, acc[i]);
            acc[i] = fmaf(hv[2], wv2, acc[i]);
            acc[i] = fmaf(hv[3], wv3, acc[i]);
        }
    }
    for (int i = 0; i < 4; ++i)
        z2[(bb * 32 + chunk * 4 + i) * 256 + t] = fmaxf(acc[i], 0.f);
}

// sage2: grid 256 = (bb, chunk of 4 nodes); o = t&127, half = t>>7 (2 nodes each).
__global__ __launch_bounds__(256) void sage2_kernel(
    const float* __restrict__ z2, const float* __restrict__ l2T,
    const float* __restrict__ lb, const float* __restrict__ w2pT,
    float* __restrict__ out) {
    const int bb = blockIdx.x >> 3, chunk = blockIdx.x & 7;
    __shared__ float h[32 * 256];
    __shared__ float sl[256];
    const int t = threadIdx.x;
    const float* zb = z2 + bb * 8192;
    for (int idx = t; idx < 8192; idx += 256) h[idx] = zb[idx];
    __syncthreads();
    float s = 0.f;
#pragma unroll
    for (int n = 0; n < 32; ++n) s += h[n * 256 + t];
    sl[t] = s * (1.f / 31.f);
    __syncthreads();
    const int o = t & 127, half = t >> 7;
    float c = lb[o];
#pragma unroll 4
    for (int d = 0; d < 256; ++d) c = fmaf(sl[d], l2T[d * 128 + o], c);
    float acc[2];
    acc[0] = c; acc[1] = c;
    const int n0 = chunk * 4 + half * 2;
    for (int d0 = 0; d0 < 256; d0 += 4) {
        float wv0 = w2pT[(d0 + 0) * 128 + o];
        float wv1 = w2pT[(d0 + 1) * 128 + o];
        float wv2 = w2pT[(d0 + 2) * 128 + o];
        float wv3 = w2pT[(d0 + 3) * 128 + o];
#pragma unroll
        for (int ii = 0; ii < 2; ++ii) {
            f32x4 hv = *(const f32x4*)&h[(n0 + ii) * 256 + d0];
            acc[ii] = fmaf(hv[0], wv0, acc[ii]);
            acc[ii] = fmaf(hv[1], wv1, acc[ii]);
            acc[ii] = fmaf(hv[2], wv2, acc[ii]);
            acc[ii] = fmaf(hv[3], wv3, acc[ii]);
        }
    }
    for (int ii = 0; ii < 2; ++ii)
        out[(size_t)(bb * 32 + n0 + ii) * 128 + o] = acc[ii];
}

extern "C" void kernel_launch(void* const* d_in, const int* in_sizes, int n_in,
                              void* d_out, int out_size, void* d_ws, size_t ws_size,
                              hipStream_t stream) {
    const float* x    = (const float*)d_in[0];
    const float* mask = (const float*)d_in[1];
    const float* c1w  = (const float*)d_in[2];
    const float* c1b  = (const float*)d_in[3];
    const float* c2w  = (const float*)d_in[4];
    const float* c2b  = (const float*)d_in[5];
    const float* fcw  = (const float*)d_in[6];
    const float* fcb  = (const float*)d_in[7];
    const float* s1lw = (const float*)d_in[8];
    const float* s1lb = (const float*)d_in[9];
    const float* s1rw = (const float*)d_in[10];
    const float* s2lw = (const float*)d_in[11];
    const float* s2lb = (const float*)d_in[12];
    const float* s2rw = (const float*)d_in[13];
    float* out = (float*)d_out;

    char* ws = (char*)d_ws;
    float* pooled4 = (float*)(ws);
    float* z1      = (float*)(ws + 2048u * 1024);
    float* z2      = (float*)(ws + 3072u * 1024);
    float* l1T     = (float*)(ws + 4096u * 1024);
    float* w1pT    = (float*)(ws + 4352u * 1024);
    float* l2T     = (float*)(ws + 4608u * 1024);
    float* w2pT    = (float*)(ws + 4736u * 1024);
    float* fwT     = (float*)(ws + 4864u * 1024);
    short* w2b     = (short*)(ws + 4992u * 1024);
    short* w1b     = (short*)(ws + 5136u * 1024);

    prep_kernel<<<dim3(288), 256, 0, stream>>>(s1lw, s1rw, s2lw, s2rw, c2w, c1w, c1b,
                                               fcw, l1T, w1pT, l2T, w2pT, fwT, w2b, w1b);
    fused_conv_kernel<<<dim3(4, 1024), 256, 0, stream>>>(x, w1b, w2b, c2b, pooled4);
    fc_kernel<<<dim3(1024), 256, 0, stream>>>(pooled4, fwT, fcb, mask, z1);
    sage1_kernel<<<dim3(256), 256, 0, stream>>>(z1, l1T, s1lb, w1pT, z2);
    sage2_kernel<<<dim3(256), 256, 0, stream>>>(z2, l2T, s2lb, w2pT, out);
}